// Round 7
// baseline (141.666 us; speedup 1.0000x reference)
//
#include <hip/hip_runtime.h>
#include <cstdint>

// ---------------------------------------------------------------------------
// JAX PRNG replication (verified bit-exact rounds 1-6, absmax 0.0).
// key(42) -> threefry2x32 key (0,42), jax_threefry_partitionable semantics.
// ---------------------------------------------------------------------------
__host__ __device__ inline void threefry2x32(uint32_t k0, uint32_t k1,
                                             uint32_t x0, uint32_t x1,
                                             uint32_t& o0, uint32_t& o1) {
  const uint32_t ks2 = k0 ^ k1 ^ 0x1BD11BDAu;
  uint32_t v0 = x0 + k0, v1 = x1 + k1;
#define RL(v, r) (((v) << (r)) | ((v) >> (32 - (r))))
#define RND4(a, b, c, d)                                                       \
  v0 += v1; v1 = RL(v1, a); v1 ^= v0;                                          \
  v0 += v1; v1 = RL(v1, b); v1 ^= v0;                                          \
  v0 += v1; v1 = RL(v1, c); v1 ^= v0;                                          \
  v0 += v1; v1 = RL(v1, d); v1 ^= v0;
  RND4(13, 15, 26, 6)  v0 += k1;  v1 += ks2 + 1u;
  RND4(17, 29, 16, 24) v0 += ks2; v1 += k0 + 2u;
  RND4(13, 15, 26, 6)  v0 += k0;  v1 += k1 + 3u;
  RND4(17, 29, 16, 24) v0 += k1;  v1 += ks2 + 4u;
  RND4(13, 15, 26, 6)  v0 += ks2; v1 += k0 + 5u;
#undef RND4
#undef RL
  o0 = v0; o1 = v1;
}

#define IN_F 512
#define OUT_F 512
#define BATCH 512

// ---------------------------------------------------------------------------
// Prep kernel, grid 192 x 256 thr.
//  Blocks 0..127: mask gen for o-quad og=bid (4 rows, bit-exact verified
//    per-row logic), written packed+coalesced: f4 Mp[og*512+i] = rows
//    4og..4og+3 at column i (consecutive lanes -> consecutive 16B ✓).
//  Blocks 128..191: transpose x -> xT[k][b] via 64x64 LDS tile (stride 65:
//    2-way bank aliasing only = free), both global sides coalesced f4.
// ---------------------------------------------------------------------------
__global__ __launch_bounds__(256) void prep_kernel(
    const float* __restrict__ x, const float* __restrict__ pw,
    float* __restrict__ Mp, float* __restrict__ xT,
    uint32_t kb0, uint32_t kb1, uint32_t kl0, uint32_t kl1) {
  const int tid = threadIdx.x;
  if (blockIdx.x < 128) {
    const int og = blockIdx.x;
    __shared__ unsigned long long words[8];
    __shared__ int cnt;
    float m[2][4];  // [j: i=tid+256j][row]
#pragma unroll 1
    for (int r = 0; r < 4; ++r) {
      const int o = 4 * og + r;
      if (tid == 0) cnt = 0;
      __syncthreads();
      bool cj[2];
#pragma unroll
      for (int j = 0; j < 2; ++j) {
        const int i = tid + 256 * j;
        const float2 w = ((const float2*)pw)[o * IN_F + i];
        const float mx = fmaxf(w.x, w.y);
        const float e0 = expf(w.x - mx);
        const float e1 = expf(w.y - mx);
        const float p = e1 / (e0 + e1);
        uint32_t h0, h1;
        threefry2x32(kb0, kb1, 0u, (uint32_t)(o * IN_F + i), h0, h1);
        const uint32_t bits = h0 ^ h1;
        const float u = __uint_as_float((bits >> 9) | 0x3F800000u) - 1.0f;
        cj[j] = u < p;
      }
#pragma unroll
      for (int j = 0; j < 2; ++j) {
        const unsigned long long bal = __ballot(cj[j]);
        if ((tid & 63) == 0) {
          words[(tid >> 6) + 4 * j] = bal;
          atomicAdd(&cnt, __popcll(bal));
        }
      }
      __syncthreads();
      if (cnt == 0 && tid == 0) {
        uint32_t c0, c1;
        threefry2x32(kl0, kl1, 0u, (uint32_t)o, c0, c1);
        const uint32_t col = (c0 ^ c1) & (IN_F - 1);
        words[col >> 6] |= (1ull << (col & 63u));
      }
      __syncthreads();
#pragma unroll
      for (int j = 0; j < 2; ++j) {
        const int i = tid + 256 * j;
        const bool sel = (words[i >> 6] >> (i & 63)) & 1ull;
        m[j][r] = sel ? 0.0f : 1e9f;
      }
      __syncthreads();  // words/cnt reused next row
    }
#pragma unroll
    for (int j = 0; j < 2; ++j) {
      const int i = tid + 256 * j;
      *(float4*)&Mp[((size_t)og * IN_F + i) * 4] =
          make_float4(m[j][0], m[j][1], m[j][2], m[j][3]);
    }
  } else {
    const int t = blockIdx.x - 128;
    const int ti = t >> 3, tj = t & 7;  // ti: b-tile, tj: k-tile
    __shared__ float tile[64][65];
    const int r0 = tid >> 4;            // 0..15
    const int c4 = (tid & 15) * 4;      // 0..60
#pragma unroll
    for (int rr = 0; rr < 4; ++rr) {
      const int r = r0 + 16 * rr;  // b within tile
      const float4 v = *(const float4*)&x[(size_t)(64 * ti + r) * IN_F + 64 * tj + c4];
      tile[r][c4 + 0] = v.x; tile[r][c4 + 1] = v.y;
      tile[r][c4 + 2] = v.z; tile[r][c4 + 3] = v.w;
    }
    __syncthreads();
#pragma unroll
    for (int it = 0; it < 4; ++it) {
      const int kr = r0 + 16 * it;  // k within tile
      const int b4 = c4;            // b quad within tile
      float4 v;
      v.x = tile[b4 + 0][kr]; v.y = tile[b4 + 1][kr];
      v.z = tile[b4 + 2][kr]; v.w = tile[b4 + 3][kr];
      *(float4*)&xT[(size_t)(64 * tj + kr) * BATCH + 64 * ti + b4] = v;
    }
  }
}

// ---------------------------------------------------------------------------
// Min-plus, LDS-free hot loop, 4 waves/SIMD TLP (R6 failed at 1 wave/SIMD,
// 41 us latency-bound with VGPR=32). Grid 256 x 1024 thr; block = (b-half bg,
// o-quad og); wave = 32-k slice (16 slices). Lane owns a b-quad (coalesced f4
// xT load), mask f4 is wave-uniform (L1 broadcast). Explicit register double
// buffer (prefetch 4 k while computing 4) keeps 8 f4 loads in flight;
// __launch_bounds__(1024,4) caps VGPR at 128 (est ~95). Per-SIMD VALU:
// 4 waves x 1024 insts x 2cy = 8192 cy = 3.4 us floor; L1 ~520 KB/CU and
// L2 128 MB both ~3.5 us, overlapped. 64 KB LDS fold of the 16 slices.
// ---------------------------------------------------------------------------
__global__ __launch_bounds__(1024, 4) void minplus_kernel(
    const float* __restrict__ xT, const float* __restrict__ Mp,
    float* __restrict__ out) {
  const int tid = threadIdx.x;
  const int lane = tid & 63;
  const int w = tid >> 6;          // k-slice 0..15
  const int bg = blockIdx.x & 1;
  const int og = blockIdx.x >> 1;  // 0..127
  const int kbase = 32 * w;

  // f4 indices: xT f4-row stride 128; lane's b-quad at 64*bg + lane
  const float4* xp = (const float4*)xT + (size_t)kbase * 128 + 64 * bg + lane;
  const float4* mp = (const float4*)Mp + (size_t)og * IN_F + kbase;

  float4 acc[4];
#pragma unroll
  for (int q = 0; q < 4; ++q) acc[q] = make_float4(1e30f, 1e30f, 1e30f, 1e30f);

  float4 xb[2][4], mb[2][4];
#pragma unroll
  for (int u = 0; u < 4; ++u) {  // prefetch group 0
    xb[0][u] = xp[(size_t)u * 128];
    mb[0][u] = mp[u];
  }
#pragma unroll 1
  for (int g = 0; g < 8; ++g) {  // 8 groups of 4 k
    const int cur = g & 1, nxt = cur ^ 1;
    if (g < 7) {
      const int k0 = 4 * (g + 1);
#pragma unroll
      for (int u = 0; u < 4; ++u) {
        xb[nxt][u] = xp[(size_t)(k0 + u) * 128];
        mb[nxt][u] = mp[k0 + u];
      }
    }
#pragma unroll
    for (int u = 0; u < 4; ++u) {
      const float4 xv = xb[cur][u];
      const float4 mv = mb[cur][u];
#pragma unroll
      for (int q = 0; q < 4; ++q) {
        const float xi = (q == 0) ? xv.x : (q == 1) ? xv.y : (q == 2) ? xv.z : xv.w;
        acc[q].x = fminf(acc[q].x, xi + mv.x);
        acc[q].y = fminf(acc[q].y, xi + mv.y);
        acc[q].z = fminf(acc[q].z, xi + mv.z);
        acc[q].w = fminf(acc[q].w, xi + mv.w);
      }
    }
  }

  // fold 16 k-slice partials
  __shared__ float4 part[16][4][64];  // 64 KB
#pragma unroll
  for (int q = 0; q < 4; ++q) part[w][q][lane] = acc[q];
  __syncthreads();

  if (tid < 256) {
    const int lane2 = tid >> 2, q2 = tid & 3;  // b_local = 4*lane2+q2 = tid
    float4 r = part[0][q2][lane2];
#pragma unroll
    for (int w2 = 1; w2 < 16; ++w2) {
      const float4 p = part[w2][q2][lane2];
      r.x = fminf(r.x, p.x); r.y = fminf(r.y, p.y);
      r.z = fminf(r.z, p.z); r.w = fminf(r.w, p.w);
    }
    *(float4*)&out[(size_t)(256 * bg + tid) * OUT_F + 4 * og] = r;
  }
}

extern "C" void kernel_launch(void* const* d_in, const int* in_sizes, int n_in,
                              void* d_out, int out_size, void* d_ws, size_t ws_size,
                              hipStream_t stream) {
  (void)in_sizes; (void)n_in; (void)out_size; (void)ws_size;
  const float* x = (const float*)d_in[0];   // [512, 512]
  const float* pw = (const float*)d_in[1];  // [512, 512, 2]
  float* Mp = (float*)d_ws;                     // 1 MB: [128 og][512 k] f4
  float* xT = (float*)d_ws + BATCH * IN_F;      // 1 MB: [512 k][512 b]
  float* out = (float*)d_out;

  uint32_t kb0, kb1, kf0, kf1, kl0, kl1;
  threefry2x32(0u, 42u, 0u, 0u, kb0, kb1);   // k_bern = hash(key; 0,0)
  threefry2x32(0u, 42u, 0u, 1u, kf0, kf1);   // k_fix  = hash(key; 0,1)
  threefry2x32(kf0, kf1, 0u, 1u, kl0, kl1);  // randint lower-bits key

  prep_kernel<<<dim3(192), dim3(256), 0, stream>>>(x, pw, Mp, xT,
                                                   kb0, kb1, kl0, kl1);
  minplus_kernel<<<dim3(256), dim3(1024), 0, stream>>>(xT, Mp, out);
}